// Round 4
// baseline (126.403 us; speedup 1.0000x reference)
//
#include <hip/hip_runtime.h>

#define B_   8
#define N_   512
#define IND  256
#define H_   4
#define PH   32
#define OD   128   // H_*PH
#define TI   4     // targets per block (attn)

typedef float v2f __attribute__((ext_vector_type(2)));

// leaky 0.4 * log2(e), and 0.6 * log2(e): logits in log2 domain -> v_exp_f32.
#define ATT_SCALE 0.5770780163555854f
#define DLR_SCALE 0.8656170245333781f

template <int PAT>
__device__ __forceinline__ float dpp_add(float x) {
    int yi = __builtin_amdgcn_mov_dpp(__float_as_int(x), PAT, 0xF, 0xF, true);
    return x + __int_as_float(yi);
}

__device__ __forceinline__ float fast_exp2(float x) {
#if __has_builtin(__builtin_amdgcn_exp2f)
    return __builtin_amdgcn_exp2f(x);
#else
    return exp2f(x);
#endif
}

// Packed fp32 FMA: d += a*b on both halves, ONE VOP3P instruction.
__device__ __forceinline__ void pk_fma(v2f& d, v2f a, v2f b) {
    asm("v_pk_fma_f32 %0, %1, %2, %0" : "+v"(d) : "v"(a), "v"(b));
}

// ---------------------------------------------------------------------------
// Kernel 1 v5: xl = x@Wl + bl ; xr = x@Wr + br  plus pre-scaled rank-1 parts.
// r3 post-mortem: v4 (512 thr, 16 waves/CU, 1-deep prefetch) was latency-
// bound at 31 us vs a 3.4 us FMA floor. v5 trades SW pipelining for pure TLP:
//   block 1024 thr (16 waves), grid 512 -> 2 blocks/CU = 32 waves/CU (full).
//   thread = 2 rows x 4 cols x 64 k, chunk = 2 k -> ~40 VGPR. Forced <=64 by
//   __launch_bounds__(1024,4) (empirical cap = 256/min_waves) so the VGPR
//   occupancy cliff at 64 (m69) is not crossed. W single-buffered: with 8
//   waves/SIMD the L2 latency is hidden by wave interleave, not prefetch.
// K-split stays 4-way (same reassociation depth as v4 -> absmax unchanged).
// ---------------------------------------------------------------------------
__global__ __launch_bounds__(1024, 4) void proj_kernel(
    const float* __restrict__ x,
    const float* __restrict__ Wl, const float* __restrict__ bl,
    const float* __restrict__ Wr, const float* __restrict__ br,
    const float* __restrict__ att,
    float* __restrict__ xl, float* __restrict__ xr,
    float* __restrict__ dl, float* __restrict__ dr)
{
    __shared__ float xs[8 * IND];        // 8 KB
    __shared__ float comb[3][256][9];    // 27 KB, pad 9 -> conflict-free

    const int t = threadIdx.x;
    const int row0 = blockIdx.x * 8;

    if (t < 512)
        ((float4*)xs)[t] = ((const float4*)(x + (size_t)row0 * IND))[t];
    __syncthreads();

    const int og    = t & 31;        // col quad: cols og*4 .. og*4+3
    const int rh    = (t >> 5) & 3;  // row pair: rows rh*2, rh*2+1
    const int ks    = (t >> 7) & 3;  // K quarter: k0 = ks*64 (wave-uniform)
    const int which = t >> 9;        // 0: Wl->xl/dl, 1: Wr->xr/dr
    const int o0 = og * 4;
    const int r0 = rh * 2;
    const int k0 = ks * 64;
    const float* W = (which ? Wr : Wl) + (size_t)k0 * OD + o0;
    const float* xsa = &xs[r0 * IND + k0];
    const float* xsb = &xs[(r0 + 1) * IND + k0];

    float acc[2][4];
    #pragma unroll
    for (int r = 0; r < 2; ++r)
        #pragma unroll
        for (int c = 0; c < 4; ++c) acc[r][c] = 0.f;

    #pragma unroll 4
    for (int s = 0; s < 32; ++s) {       // 32 chunks of 2 k
        float4 w0 = *(const float4*)(W + (size_t)(2 * s) * OD);
        float4 w1 = *(const float4*)(W + (size_t)(2 * s + 1) * OD);
        float2 xa = *(const float2*)(xsa + 2 * s);
        float2 xb = *(const float2*)(xsb + 2 * s);
        acc[0][0] = fmaf(xa.x, w0.x, acc[0][0]);
        acc[0][1] = fmaf(xa.x, w0.y, acc[0][1]);
        acc[0][2] = fmaf(xa.x, w0.z, acc[0][2]);
        acc[0][3] = fmaf(xa.x, w0.w, acc[0][3]);
        acc[1][0] = fmaf(xb.x, w0.x, acc[1][0]);
        acc[1][1] = fmaf(xb.x, w0.y, acc[1][1]);
        acc[1][2] = fmaf(xb.x, w0.z, acc[1][2]);
        acc[1][3] = fmaf(xb.x, w0.w, acc[1][3]);
        acc[0][0] = fmaf(xa.y, w1.x, acc[0][0]);
        acc[0][1] = fmaf(xa.y, w1.y, acc[0][1]);
        acc[0][2] = fmaf(xa.y, w1.z, acc[0][2]);
        acc[0][3] = fmaf(xa.y, w1.w, acc[0][3]);
        acc[1][0] = fmaf(xb.y, w1.x, acc[1][0]);
        acc[1][1] = fmaf(xb.y, w1.y, acc[1][1]);
        acc[1][2] = fmaf(xb.y, w1.z, acc[1][2]);
        acc[1][3] = fmaf(xb.y, w1.w, acc[1][3]);
    }

    // combine K-quarters: ks=1..3 stage partials, ks=0 sums + writes
    const int pid = og | (rh << 5) | (which << 7);   // 0..255
    if (ks != 0) {
        #pragma unroll
        for (int i = 0; i < 8; ++i)
            comb[ks - 1][pid][i] = acc[i >> 2][i & 3];
    }
    __syncthreads();
    if (ks == 0) {
        const float* bb = which ? br : bl;
        float* dst = which ? xr : xl;
        float* dp  = which ? dr : dl;
        float4 bv = *(const float4*)(bb + o0);
        float4 av = *(const float4*)(att + o0);
        const float bvf[4] = {bv.x, bv.y, bv.z, bv.w};
        const float avf[4] = {av.x, av.y, av.z, av.w};
        #pragma unroll
        for (int r = 0; r < 2; ++r) {
            float y[4];
            #pragma unroll
            for (int c = 0; c < 4; ++c)
                y[c] = ((acc[r][c] + comb[0][pid][r * 4 + c])
                      + (comb[1][pid][r * 4 + c] + comb[2][pid][r * 4 + c]))
                      + bvf[c];
            *(float4*)(&dst[(size_t)(row0 + r0 + r) * OD + o0]) =
                make_float4(y[0], y[1], y[2], y[3]);
            // rank-1 part: dl/dr[n,h] = 0.6*log2e * sum_c att[h,c]*y[c]
            float dc = fmaf(avf[0], y[0], fmaf(avf[1], y[1],
                       fmaf(avf[2], y[2], avf[3] * y[3])));
            dc += __shfl_xor(dc, 1);
            dc += __shfl_xor(dc, 2);
            dc += __shfl_xor(dc, 4);   // sums the 8 og-lanes of one head
            if ((og & 7) == 0)
                dp[(size_t)(row0 + r0 + r) * H_ + (og >> 3)] = DLR_SCALE * dc;
        }
    }
}

// ---------------------------------------------------------------------------
// Kernel 2 v5: masked-softmax attention aggregate. Measured across r0/r3:
// TI=4 beats TI=2 by ~14% (per-j xl/adj/dl load cost amortizes over 4
// targets). This is round-0's TI=4 kernel (68 VGPR, no spill @ (256,3))
// plus the two fixes round-3 PROVED on counters:
//   * XCD<->batch swizzle (FETCH 42 -> 6 MB measured)   [1024 = 8 x 128]
//   * epilogue LDS dims [h][il][js][c]: write banks (js+8cq)%32 <=2-way
//     (free), was 16-way / 262K conflict cycles in round-0.
// ---------------------------------------------------------------------------
__global__ __launch_bounds__(256, 3) void attn_kernel(
    const int* __restrict__ adj, const float* __restrict__ att,
    const float* __restrict__ bias,
    const float* __restrict__ xl, const float* __restrict__ xr,
    const float* __restrict__ dl, const float* __restrict__ dr,
    float* __restrict__ out)
{
    __shared__ float sacc[H_][TI][16][PH + 1];  // 33 KB
    __shared__ float ssum[H_][16][TI];          // 1 KB

    const int t = threadIdx.x;
    const int bid = (blockIdx.x & 7) * 128 + (blockIdx.x >> 3);
    const int b  = bid >> 7;
    const int i0 = (bid & 127) * TI;
    const int cq = t & 3;
    const int js = (t >> 2) & 15;
    const int h  = t >> 6;
    const int cbase = h * PH + cq * 8;

    // preload att (pre-scaled by 0.4*log2e) and xr fragments for all 4 targets
    float atS[8];
    {
        const float* ap = att + cbase;
        float4 a0 = *(const float4*)(ap);
        float4 a1 = *(const float4*)(ap + 4);
        atS[0] = ATT_SCALE * a0.x; atS[1] = ATT_SCALE * a0.y;
        atS[2] = ATT_SCALE * a0.z; atS[3] = ATT_SCALE * a0.w;
        atS[4] = ATT_SCALE * a1.x; atS[5] = ATT_SCALE * a1.y;
        atS[6] = ATT_SCALE * a1.z; atS[7] = ATT_SCALE * a1.w;
    }
    float xrS[TI][8];
    float drv[TI];
    #pragma unroll
    for (int il = 0; il < TI; ++il) {
        const float* xp = xr + ((size_t)(b * N_ + i0 + il)) * OD + cbase;
        float4 r0 = *(const float4*)(xp);
        float4 r1 = *(const float4*)(xp + 4);
        xrS[il][0] = r0.x; xrS[il][1] = r0.y; xrS[il][2] = r0.z; xrS[il][3] = r0.w;
        xrS[il][4] = r1.x; xrS[il][5] = r1.y; xrS[il][6] = r1.z; xrS[il][7] = r1.w;
        drv[il] = dr[((size_t)(b * N_ + i0 + il)) * H_ + h];  // pre-scaled
    }

    v2f acc[TI][4];
    float sumw[TI];
    #pragma unroll
    for (int il = 0; il < TI; ++il) {
        sumw[il] = 0.f;
        #pragma unroll
        for (int m = 0; m < 4; ++m) acc[il][m] = (v2f){0.f, 0.f};
    }

    // software-pipelined j-loop: j = u*16 + js, u = 0..31
    const float* xlp = xl + ((size_t)(b * N_ + js)) * OD + cbase;
    const int*   ajp = adj + ((size_t)(b * N_ + js)) * N_ + i0;
    const float* dlp = dl + ((size_t)(b * N_ + js)) * H_ + h;

    float4 va = *(const float4*)(xlp);
    float4 vb = *(const float4*)(xlp + 4);
    int4   mj = *(const int4*)(ajp);
    float  dj = *dlp;

    #pragma unroll 2
    for (int u = 0; u < 32; ++u) {
        float4 wa = va, wb = vb;
        int4   wm = mj;
        float  wd = dj;
        if (u < 31) {
            xlp += 16 * OD; ajp += 16 * N_; dlp += 16 * H_;
            va = *(const float4*)(xlp);
            vb = *(const float4*)(xlp + 4);
            mj = *(const int4*)(ajp);
            dj = *dlp;
        }
        const int j = u * 16 + js;
        v2f p0 = (v2f){wa.x, wa.y}, p1 = (v2f){wa.z, wa.w};
        v2f p2 = (v2f){wb.x, wb.y}, p3 = (v2f){wb.z, wb.w};
        int wmv[TI] = {wm.x, wm.y, wm.z, wm.w};
        #pragma unroll
        for (int il = 0; il < TI; ++il) {
            float s, e2a = 0.f, e2b = 0.f;
            s = xrS[il][0] + wa.x; e2a = fmaf(atS[0], __builtin_fabsf(s), e2a);
            s = xrS[il][1] + wa.y; e2b = fmaf(atS[1], __builtin_fabsf(s), e2b);
            s = xrS[il][2] + wa.z; e2a = fmaf(atS[2], __builtin_fabsf(s), e2a);
            s = xrS[il][3] + wa.w; e2b = fmaf(atS[3], __builtin_fabsf(s), e2b);
            s = xrS[il][4] + wb.x; e2a = fmaf(atS[4], __builtin_fabsf(s), e2a);
            s = xrS[il][5] + wb.y; e2b = fmaf(atS[5], __builtin_fabsf(s), e2b);
            s = xrS[il][6] + wb.z; e2a = fmaf(atS[6], __builtin_fabsf(s), e2a);
            s = xrS[il][7] + wb.w; e2b = fmaf(atS[7], __builtin_fabsf(s), e2b);
            float eh = e2a + e2b;
            eh = dpp_add<0xB1>(eh);          // + lane^1 (quad_perm 1,0,3,2)
            eh = dpp_add<0x4E>(eh);          // + lane^2 (quad_perm 2,3,0,1)
            float e = (wd + drv[il]) + eh;   // full log2-domain logit
            bool keep = (wmv[il] != 0) || (j == i0 + il);
            float w = keep ? fast_exp2(e) : 0.f;
            sumw[il] += w;
            v2f ws = (v2f){w, w};
            pk_fma(acc[il][0], ws, p0);
            pk_fma(acc[il][1], ws, p1);
            pk_fma(acc[il][2], ws, p2);
            pk_fma(acc[il][3], ws, p3);
        }
    }

    // ---- epilogue: LDS transpose + reduce over the 16 js slices ----
    #pragma unroll
    for (int il = 0; il < TI; ++il) {
        float4 w0 = make_float4(acc[il][0].x, acc[il][0].y,
                                acc[il][1].x, acc[il][1].y);
        float4 w1 = make_float4(acc[il][2].x, acc[il][2].y,
                                acc[il][3].x, acc[il][3].y);
        *(float4*)(&sacc[h][il][js][cq * 8])     = w0;
        *(float4*)(&sacc[h][il][js][cq * 8 + 4]) = w1;
    }
    if (cq == 0) {
        #pragma unroll
        for (int il = 0; il < TI; ++il)
            ssum[h][js][il] = sumw[il];
    }
    __syncthreads();

    const int lane = t & 63;
    const int o = lane * 2;          // output pair within this head
    const int il2 = o >> 5;          // 0..3
    const int c2 = o & 31;           // 0..30 even
    float st = 0.f;
    #pragma unroll
    for (int k = 0; k < 16; ++k) st += ssum[h][k][il2];
    float a0 = 0.f, a1 = 0.f;
    #pragma unroll
    for (int k = 0; k < 16; ++k) {
        float2 p = *(const float2*)(&sacc[h][il2][k][c2]);
        a0 += p.x; a1 += p.y;
    }
    const float inv = 1.f / st;
    const int c = h * PH + c2;
    float* op = out + ((size_t)(b * N_ + i0 + il2)) * OD;
    *(float2*)(&op[c]) = make_float2(fmaf(a0, inv, bias[c]),
                                     fmaf(a1, inv, bias[c + 1]));
}

extern "C" void kernel_launch(void* const* d_in, const int* in_sizes, int n_in,
                              void* d_out, int out_size, void* d_ws, size_t ws_size,
                              hipStream_t stream) {
    const float* x    = (const float*)d_in[0];
    const int*   adj  = (const int*)d_in[1];
    const float* Wl   = (const float*)d_in[2];
    const float* bl   = (const float*)d_in[3];
    const float* Wr   = (const float*)d_in[4];
    const float* br   = (const float*)d_in[5];
    const float* att  = (const float*)d_in[6];
    const float* bias = (const float*)d_in[7];
    float* out = (float*)d_out;

    float* xl = (float*)d_ws;                    // 2 MB
    float* xr = xl + (size_t)B_ * N_ * OD;       // 2 MB
    float* dl = xr + (size_t)B_ * N_ * OD;       // 64 KB
    float* dr = dl + (size_t)B_ * N_ * H_;       // 64 KB

    proj_kernel<<<512, 1024, 0, stream>>>(x, Wl, bl, Wr, br, att, xl, xr, dl, dr);
    attn_kernel<<<1024, 256, 0, stream>>>(adj, att, bias, xl, xr, dl, dr, out);
}